// Round 20
// baseline (113.264 us; speedup 1.0000x reference)
//
#include <hip/hip_runtime.h>

// SDFLoss: P=64 people, V=6890 verts, 32^3 SDF-band proxy grid, trilinear
// cross-sampling, scalar loss.
//
// 3 kernels (r19 structure, proven 102.0us):
//   k_soa_bounds : bbox + translated verts SPATIALLY SORTED into vertsT by
//                  (z-cell,y-cell) counting sort (1024 buckets, own frame).
//                  Sorting is affine-invariant -> wave lanes sample coherent
//                  grid rows in every person-i frame -> LDS conflicts ~0.
//                  (Sum over verts is order-invariant; permutation is safe.)
//   k_phi        : fp8 pair volume (z-slab + wave y-row culls); block 0 also
//                  computes validity/jlist/nv/center+s16   [r19 verbatim]
//   k_sample     : stage pair volume, counted j-loop over global scalar
//                  jlist, last-block finalize               [r19 verbatim]
//
// phi: fully zero-padded PAIR volume, u16 at (iz,iy,ix), idx 0..33 = grid
// -1..32, holding (phi[gx], phi[gx+1]) as 2x fp8(e4m3) scaled x64.
// 34^3 x 2B = 78,608 B -> 2 blocks/CU in k_sample.

#define NP 64
#define NVERT 6890
#define NV3 (NVERT*3)
#define GRD 32
#define QDIM 34                   // -1..32 per axis
#define QPLANE (QDIM*QDIM)        // 1156 entries
#define QVOL (QDIM*QPLANE)        // 39304 entries = 78608 B
#define VSUB 256
#define VSTRIDE 26                // NVERT / VSUB
#define BAND 0.15f
#define PHI_SCALE 64.0f
#define INV_PHI_SCALE 0.015625f
#define LDS_BYTES (QVOL*2 + 64)
#define SAMPLE_BLOCKS (8*NP)

// k_soa LDS layout (bytes)
#define OFF_VX   0                         // f32[6890]
#define OFF_VY   27560
#define OFF_VZ   55120
#define OFF_KEY  82680                     // u16[6890]
#define OFF_HIST 96464                     // u32[1024]
#define OFF_RED  100560                    // f32[16][6]
#define LDS_SOA  100960

typedef float floatx2 __attribute__((ext_vector_type(2)));

__device__ __forceinline__ float wave_min(float v) {
  #pragma unroll
  for (int off = 32; off > 0; off >>= 1) v = fminf(v, __shfl_down(v, off));
  return v;
}
__device__ __forceinline__ float wave_max(float v) {
  #pragma unroll
  for (int off = 32; off > 0; off >>= 1) v = fmaxf(v, __shfl_down(v, off));
  return v;
}
__device__ __forceinline__ float wave_sum(float v) {
  #pragma unroll
  for (int off = 32; off > 0; off >>= 1) v += __shfl_down(v, off);
  return v;
}

// -------- kernel 1: bbox + (z,y)-cell counting-sorted SoA + zero accs -------
// 64 blocks x 1024 threads, ~101 KB dynamic LDS (1 block/CU).
__global__ __launch_bounds__(1024) void k_soa_bounds(
    const float* __restrict__ verts, const float* __restrict__ trans,
    float* __restrict__ vertsT, float* __restrict__ bbox,
    float* __restrict__ accp, unsigned int* __restrict__ donep) {
  extern __shared__ unsigned char smem[];
  float* vx = (float*)(smem + OFF_VX);
  float* vy = (float*)(smem + OFF_VY);
  float* vz = (float*)(smem + OFF_VZ);
  unsigned short* keys = (unsigned short*)(smem + OFF_KEY);
  int* hist = (int*)(smem + OFF_HIST);
  float* s = (float*)(smem + OFF_RED);

  int p = blockIdx.x;
  int tid = threadIdx.x;
  if (p == 0 && tid == 0) { accp[0] = 0.0f; donep[0] = 0u; }
  const float* vp = verts + (size_t)p * NV3;
  float tx = trans[p*3+0], ty = trans[p*3+1], tz = trans[p*3+2];

  // pass A: load pairs, translate into LDS, track bbox
  float mnx=1e30f, mny=1e30f, mnz=1e30f, mxx=-1e30f, mxy=-1e30f, mxz=-1e30f;
  for (int t2 = tid; t2 < NVERT/2; t2 += 1024) {   // 3445 vert-pairs (V even)
    const float* b = vp + t2*6;
    floatx2 A = *(const floatx2*)(b);      // (x0, y0)
    floatx2 B = *(const floatx2*)(b+2);    // (z0, x1)
    floatx2 C = *(const floatx2*)(b+4);    // (y1, z1)
    mnx=fminf(mnx,fminf(A.x,B.y)); mxx=fmaxf(mxx,fmaxf(A.x,B.y));
    mny=fminf(mny,fminf(A.y,C.x)); mxy=fmaxf(mxy,fmaxf(A.y,C.x));
    mnz=fminf(mnz,fminf(B.x,C.y)); mxz=fmaxf(mxz,fmaxf(B.x,C.y));
    vx[2*t2] = A.x+tx; vx[2*t2+1] = B.y+tx;
    vy[2*t2] = A.y+ty; vy[2*t2+1] = C.x+ty;
    vz[2*t2] = B.x+tz; vz[2*t2+1] = C.y+tz;
  }
  mnx=wave_min(mnx)+tx; mny=wave_min(mny)+ty; mnz=wave_min(mnz)+tz;
  mxx=wave_max(mxx)+tx; mxy=wave_max(mxy)+ty; mxz=wave_max(mxz)+tz;
  int wave = tid >> 6, lane = tid & 63;
  if (lane == 0) {
    s[wave*6+0]=mnx; s[wave*6+1]=mny; s[wave*6+2]=mnz;
    s[wave*6+3]=mxx; s[wave*6+4]=mxy; s[wave*6+5]=mxz;
  }
  if (tid < 1024) hist[tid] = 0;
  __syncthreads();
  if (tid == 0) {
    float a0=s[0],a1=s[1],a2=s[2],b0=s[3],b1=s[4],b2=s[5];
    for (int w = 1; w < 16; ++w) {
      a0=fminf(a0,s[w*6+0]); a1=fminf(a1,s[w*6+1]); a2=fminf(a2,s[w*6+2]);
      b0=fmaxf(b0,s[w*6+3]); b1=fmaxf(b1,s[w*6+4]); b2=fmaxf(b2,s[w*6+5]);
    }
    bbox[p*3+0]=a0; bbox[p*3+1]=a1; bbox[p*3+2]=a2;              // bmin
    bbox[192+p*3+0]=b0; bbox[192+p*3+1]=b1; bbox[192+p*3+2]=b2;  // bmax
    s[0]=a0; s[1]=a1; s[2]=a2; s[3]=b0; s[4]=b1; s[5]=b2;
  }
  __syncthreads();
  float cy = 0.5f*(s[1]+s[4]), cz = 0.5f*(s[2]+s[5]);
  float ext = fmaxf(s[3]-s[0], fmaxf(s[4]-s[1], s[5]-s[2]));
  float is16 = 16.0f / (0.6f * ext);    // cell coord scale: (n+1)*16

  // pass B: per-vert bucket key (zc*32+yc in own frame) + histogram
  for (int v = tid; v < NVERT; v += 1024) {
    float Yn = (vy[v] - cy) * is16 + 16.0f;   // 0..32 range
    float Zn = (vz[v] - cz) * is16 + 16.0f;
    int yc = (int)fminf(fmaxf(Yn, 0.0f), 31.0f);
    int zc = (int)fminf(fmaxf(Zn, 0.0f), 31.0f);
    int key = zc*32 + yc;
    keys[v] = (unsigned short)key;
    atomicAdd(&hist[key], 1);
  }
  __syncthreads();

  // exclusive prefix over 1024 buckets: wave 0, 16 buckets/lane
  if (tid < 64) {
    int base = tid * 16;
    int mysum = 0;
    #pragma unroll
    for (int k = 0; k < 16; ++k) mysum += hist[base+k];
    int scan = mysum;
    #pragma unroll
    for (int off = 1; off < 64; off <<= 1) {
      int n = __shfl_up(scan, off);
      if (tid >= off) scan += n;
    }
    int run = scan - mysum;                   // exclusive base
    #pragma unroll
    for (int k = 0; k < 16; ++k) {
      int old = hist[base+k]; hist[base+k] = run; run += old;
    }
  }
  __syncthreads();

  // pass C: scatter into sorted SoA (hist doubles as cursor)
  float* o0 = vertsT + (size_t)(p*3+0) * NVERT;
  float* o1 = vertsT + (size_t)(p*3+1) * NVERT;
  float* o2 = vertsT + (size_t)(p*3+2) * NVERT;
  for (int v = tid; v < NVERT; v += 1024) {
    int key = keys[v];
    int dst = atomicAdd(&hist[key], 1);
    o0[dst] = vx[v]; o1[dst] = vy[v]; o2[dst] = vz[v];
  }
}

// -------- kernel 2: phi pair volume + (block 0) setup outputs [r19] --------
__global__ __launch_bounds__(1024) void k_phi(
    const float* __restrict__ verts, const float* __restrict__ trans,
    const float* __restrict__ bbox, unsigned short* __restrict__ pairs,
    float* __restrict__ centerg,   // [NP][4] = cx,cy,cz,s16
    float* __restrict__ validg, int* __restrict__ jlistg,
    int* __restrict__ jcountg, float* __restrict__ nvg) {
  int p = blockIdx.x >> 2;
  int zq = blockIdx.x & 3;
  int tid = threadIdx.x;
  int x = tid & 31, y = tid >> 5;

  __shared__ float kv[VSUB][3];       // z-culled vertex list
  __shared__ float phib[8][32][32];   // 32 KB
  __shared__ int nkeep;

  const float inv = 1.0f / (float)GRD;
  if (tid == 0) nkeep = 0;
  __syncthreads();

  // center/scale from bbox
  float bx0 = bbox[p*3+0], by0 = bbox[p*3+1], bz0 = bbox[p*3+2];
  float bx1 = bbox[192+p*3+0], by1 = bbox[192+p*3+1], bz1 = bbox[192+p*3+2];
  float cx = 0.5f*(bx0+bx1), cy = 0.5f*(by0+by1), cz = 0.5f*(bz0+bz1);
  float ext = fmaxf(bx1-bx0, fmaxf(by1-by0, bz1-bz0));
  float is = 1.0f / (0.6f * ext);      // (1+0.2)*0.5 * ext

  // zq==0 block publishes person p's center + sample scale
  if (zq == 0 && tid == 0) {
    centerg[p*4+0] = cx; centerg[p*4+1] = cy; centerg[p*4+2] = cz;
    centerg[p*4+3] = is * 16.0f;
  }
  // block 0, wave 0: validity mask / jlist / counts
  if (blockIdx.x == 0 && tid < 64) {
    bool valid = true;
    for (int j = 0; j < NP; ++j) {
      bool ov = true;
      #pragma unroll
      for (int c = 0; c < 3; ++c)
        ov = ov && (bbox[tid*3+c] <= bbox[192+j*3+c]) &&
                   (bbox[j*3+c] <= bbox[192+tid*3+c]);
      valid = valid && ov;
    }
    unsigned long long mm = __ballot(valid);
    if (valid) {
      int pos = (int)__popcll(mm & ((1ull << tid) - 1ull));
      jlistg[pos] = tid;
    }
    validg[tid] = valid ? 1.0f : 0.0f;
    if (tid == 0) {
      jcountg[0] = (int)__popcll(mm);
      nvg[0] = (float)__popcll(mm);
    }
  }

  // z-slab cull: vert can only matter if z-distance to slab range < BAND
  if (tid < VSUB) {
    int v = tid * VSTRIDE;
    const float* vp = verts + (size_t)p * NV3 + (size_t)v * 3;
    float X = (vp[0] + trans[p*3+0] - cx) * is;
    float Y = (vp[1] + trans[p*3+1] - cy) * is;
    float Z = (vp[2] + trans[p*3+2] - cz) * is;
    float zlo = (2.0f*(zq*8)     + 1.0f) * inv - 1.0f;
    float zhi = (2.0f*(zq*8 + 7) + 1.0f) * inv - 1.0f;
    float dz = fmaxf(fmaxf(zlo - Z, Z - zhi), 0.0f);
    if (dz < BAND) {
      int idx = atomicAdd(&nkeep, 1);
      kv[idx][0] = X; kv[idx][1] = Y; kv[idx][2] = Z;
    }
  }
  __syncthreads();
  int nk = nkeep;

  float gx = (2.0f*x + 1.0f) * inv - 1.0f;
  float gy = (2.0f*y + 1.0f) * inv - 1.0f;
  float gz[8];
  #pragma unroll
  for (int k = 0; k < 8; ++k) gz[k] = (2.0f*(zq*8+k) + 1.0f) * inv - 1.0f;

  float d2[8];
  #pragma unroll
  for (int k = 0; k < 8; ++k) d2[k] = 1e30f;

  // per-wave y-row cull: wave w owns rows y = {2w, 2w+1}
  int w = tid >> 6;
  float ylo = (4.0f*w + 1.0f) * inv - 1.0f;
  float yhi = (4.0f*w + 3.0f) * inv - 1.0f;

  for (int v = 0; v < nk; ++v) {
    float Y = kv[v][1];                              // broadcast read
    if (fmaxf(ylo - Y, Y - yhi) >= BAND) continue;   // wave-uniform skip
    float dx = gx - kv[v][0];
    float dy = gy - Y;
    float vzv = kv[v][2];
    float r2 = fmaf(dy, dy, dx*dx);
    #pragma unroll
    for (int k = 0; k < 8; ++k) {
      float dz = gz[k] - vzv;
      d2[k] = fminf(d2[k], fmaf(dz, dz, r2));
    }
  }
  #pragma unroll
  for (int k = 0; k < 8; ++k)
    phib[k][y][x] = fmaxf(BAND - sqrtf(d2[k]), 0.0f) * PHI_SCALE;
  __syncthreads();

  // pair assembly: u16 at (iz, iy, ix); gy = iy-1, gx = ix-1
  unsigned short* qp = pairs + (size_t)p * QVOL;
  for (int idx = tid; idx < QPLANE; idx += 1024) {
    int iy = idx / QDIM, ix = idx % QDIM;
    int gyy = iy - 1, gxx = ix - 1;
    bool gyok = (unsigned)gyy < 32u;
    bool aok = gyok && ((unsigned)gxx < 32u);
    bool bok = gyok && ((unsigned)ix  < 32u);
    int ya = gyok ? gyy : 0;
    int xa = aok ? gxx : 0;
    int xb = bok ? ix : 0;
    #pragma unroll
    for (int k = 0; k < 8; ++k) {
      float a = aok ? phib[k][ya][xa] : 0.0f;
      float b = bok ? phib[k][ya][xb] : 0.0f;
      int pk = __builtin_amdgcn_cvt_pk_fp8_f32(a, b, 0, false);
      qp[(zq*8 + k + 1)*QPLANE + idx] = (unsigned short)(pk & 0xffff);
    }
    if (zq == 0) qp[idx] = 0;                  // plane 0  (gz = -1)
    if (zq == 3) qp[33*QPLANE + idx] = 0;      // plane 33 (gz = 32)
  }
}

// -------- trilinear sample from the LDS pair volume --------
__device__ __forceinline__ float qsample(const unsigned short* q,
                                         float X, float Y, float Z) {
  X = fminf(fmaxf(X, 0.0f), 33.99f);
  Y = fminf(fmaxf(Y, 0.0f), 32.999f);
  Z = fminf(fmaxf(Z, 0.0f), 32.999f);
  float xf = floorf(X), yf = floorf(Y), zf = floorf(Z);
  float fx = X - xf, fy = Y - yf, fz = Z - zf;
  int e = ((int)zf * QDIM + (int)yf) * QDIM + (int)xf;
  unsigned int w00 = q[e];
  unsigned int w10 = q[e + QDIM];
  unsigned int w01 = q[e + QPLANE];
  unsigned int w11 = q[e + QPLANE + QDIM];
  floatx2 c00 = __builtin_amdgcn_cvt_pk_f32_fp8((int)w00, false);
  floatx2 c10 = __builtin_amdgcn_cvt_pk_f32_fp8((int)w10, false);
  floatx2 c01 = __builtin_amdgcn_cvt_pk_f32_fp8((int)w01, false);
  floatx2 c11 = __builtin_amdgcn_cvt_pk_f32_fp8((int)w11, false);
  float u00 = fmaf(fx, c00.y - c00.x, c00.x);
  float u10 = fmaf(fx, c10.y - c10.x, c10.x);
  float u01 = fmaf(fx, c01.y - c01.x, c01.x);
  float u11 = fmaf(fx, c11.y - c11.x, c11.x);
  float a0 = fmaf(fy, u10 - u00, u00);
  float a1 = fmaf(fy, u11 - u01, u01);
  return fmaf(fz, a1 - a0, a0);
}

// -------- kernel 3: r19-verbatim sample + reduce + last-block finalize ------
__global__ __launch_bounds__(896, 7) void k_sample(
    const float* __restrict__ vertsT, const float* __restrict__ centerg,
    const float* __restrict__ validg, const unsigned short* __restrict__ pairs,
    const int* __restrict__ jlistg, const int* __restrict__ jcountg,
    const float* __restrict__ nvg, float* __restrict__ accp,
    unsigned int* __restrict__ donep, float* __restrict__ out) {
  extern __shared__ unsigned char smem[];
  const unsigned short* sq = (const unsigned short*)smem;
  float* red = (float*)(smem + (size_t)QVOL * 2);

  int i = blockIdx.y;
  int tid = threadIdx.x;
  int njl = jcountg[0];

  if (validg[i] != 0.0f) {
    // stage pair volume (78608 B = 4913 uint4) into LDS, immediately
    {
      const uint4* src = (const uint4*)(pairs + (size_t)i * QVOL);
      uint4* dst = (uint4*)smem;
      for (int t = tid; t < QVOL/8; t += 896) dst[t] = src[t];
    }
    __syncthreads();

    int v = blockIdx.x * 896 + tid;
    bool ok = v < NVERT;
    int vc = ok ? v : 0;
    float s16 = centerg[i*4+3];
    // +1 volume-index offset folded: 15.5 + 1 = 16.5
    float bx = fmaf(-centerg[i*4+0], s16, 16.5f) + (ok ? 0.0f : 1e9f);
    float by = fmaf(-centerg[i*4+1], s16, 16.5f);
    float bz = fmaf(-centerg[i*4+2], s16, 16.5f);

    float acc = 0.0f;
    #pragma unroll 2
    for (int t = 0; t < njl; ++t) {
      int jj = jlistg[t];                      // uniform -> scalar load/branch
      if (jj == i) continue;
      const float* p0 = vertsT + (size_t)(jj*3) * NVERT;
      float X = fmaf(p0[vc],         s16, bx);
      float Y = fmaf(p0[NVERT+vc],   s16, by);
      float Z = fmaf(p0[2*NVERT+vc], s16, bz);
      acc += qsample(sq, X, Y, Z);
    }

    acc = wave_sum(acc);
    int wv = tid >> 6, lane = tid & 63;
    if (lane == 0) red[wv] = acc;
    __syncthreads();
    if (tid == 0) {
      float tot = 0.0f;
      #pragma unroll
      for (int w = 0; w < 14; ++w) tot += red[w];
      atomicAdd(accp, tot * INV_PHI_SCALE);
    }
  }

  // last-block finalize; every block increments
  if (tid == 0) {
    __threadfence();
    unsigned int old = atomicAdd(donep, 1u);
    if (old == SAMPLE_BLOCKS - 1) {
      float nv = fmaxf(nvg[0], 1.0f);
      float loss = atomicAdd(accp, 0.0f);      // coherent read
      out[0] = loss / (nv * nv);
    }
  }
}

extern "C" void kernel_launch(void* const* d_in, const int* in_sizes, int n_in,
                              void* d_out, int out_size, void* d_ws, size_t ws_size,
                              hipStream_t stream) {
  const float* verts = (const float*)d_in[0];   // [64,6890,3]
  const float* trans = (const float*)d_in[1];   // [64,3]
  float* out = (float*)d_out;

  unsigned short* pairs = (unsigned short*)d_ws;      // 64*39304*2 B = 5.03 MB
  float* vertsT    = (float*)((unsigned char*)d_ws + (size_t)NP * QVOL * 2);
  float* bbox      = vertsT + (size_t)NP * NV3;       // bmin[192] ++ bmax[192]
  float* centerg   = bbox + 384;                      // [NP][4]
  float* validg    = centerg + NP*4;
  float* nvg       = validg + NP;
  float* accp      = nvg + 1;
  unsigned int* donep = (unsigned int*)(accp + 1);
  int* jlistg      = (int*)(donep + 1);
  int* jcountg     = jlistg + NP;

  hipFuncSetAttribute((const void*)k_soa_bounds,
                      hipFuncAttributeMaxDynamicSharedMemorySize, LDS_SOA);
  hipFuncSetAttribute((const void*)k_sample,
                      hipFuncAttributeMaxDynamicSharedMemorySize, LDS_BYTES);

  k_soa_bounds<<<NP, 1024, LDS_SOA, stream>>>(verts, trans, vertsT, bbox,
                                              accp, donep);
  k_phi<<<NP*4, 1024, 0, stream>>>(verts, trans, bbox, pairs, centerg,
                                   validg, jlistg, jcountg, nvg);
  k_sample<<<dim3(8, NP), 896, LDS_BYTES, stream>>>(vertsT, centerg, validg,
                                                    pairs, jlistg, jcountg,
                                                    nvg, accp, donep, out);
}

// Round 21
// 103.211 us; speedup vs baseline: 1.0974x; 1.0974x over previous
//
#include <hip/hip_runtime.h>

// SDFLoss: P=64 people, V=6890 verts, 32^3 SDF-band proxy grid, trilinear
// cross-sampling, scalar loss.
//
// 3 kernels (r19 structure, proven 102.0us; k_sample ILP-doubled):
//   k_soa_bounds : float2-pair vectorized SoA verts + bbox + zero accs [r19]
//   k_phi        : fp8 pair volume (z-slab + wave y-row culls); block 0 also
//                  computes validity/jlist/nv/center+s16   [r19 verbatim]
//   k_sample     : 4 chunks x 2 vert slots/thread (256 blocks, half the
//                  staging, 2 independent sample chains per j-iteration);
//                  counted j-loop over global scalar jlist; last-block
//                  finalize.
//
// phi: fully zero-padded PAIR volume, u16 at (iz,iy,ix), idx 0..33 = grid
// -1..32, holding (phi[gx], phi[gx+1]) as 2x fp8(e4m3) scaled x64.
// 34^3 x 2B = 78,608 B -> 2 blocks/CU in k_sample.

#define NP 64
#define NVERT 6890
#define NV3 (NVERT*3)
#define GRD 32
#define QDIM 34                   // -1..32 per axis
#define QPLANE (QDIM*QDIM)        // 1156 entries
#define QVOL (QDIM*QPLANE)        // 39304 entries = 78608 B
#define VSUB 256
#define VSTRIDE 26                // NVERT / VSUB
#define BAND 0.15f
#define PHI_SCALE 64.0f
#define INV_PHI_SCALE 0.015625f
#define LDS_BYTES (QVOL*2 + 64)
#define SAMPLE_BLOCKS (4*NP)

typedef float floatx2 __attribute__((ext_vector_type(2)));

__device__ __forceinline__ float wave_min(float v) {
  #pragma unroll
  for (int off = 32; off > 0; off >>= 1) v = fminf(v, __shfl_down(v, off));
  return v;
}
__device__ __forceinline__ float wave_max(float v) {
  #pragma unroll
  for (int off = 32; off > 0; off >>= 1) v = fmaxf(v, __shfl_down(v, off));
  return v;
}
__device__ __forceinline__ float wave_sum(float v) {
  #pragma unroll
  for (int off = 32; off > 0; off >>= 1) v += __shfl_down(v, off);
  return v;
}

// -------- kernel 1: vectorized SoA verts + bbox + zero accs [r19] --------
__global__ __launch_bounds__(1024) void k_soa_bounds(
    const float* __restrict__ verts, const float* __restrict__ trans,
    float* __restrict__ vertsT, float* __restrict__ bbox,
    float* __restrict__ accp, unsigned int* __restrict__ donep) {
  int p = blockIdx.x;
  int tid = threadIdx.x;
  if (p == 0 && tid == 0) { accp[0] = 0.0f; donep[0] = 0u; }
  const float* vp = verts + (size_t)p * NV3;
  float tx = trans[p*3+0], ty = trans[p*3+1], tz = trans[p*3+2];
  float* o0 = vertsT + (size_t)(p*3+0) * NVERT;
  float* o1 = vertsT + (size_t)(p*3+1) * NVERT;
  float* o2 = vertsT + (size_t)(p*3+2) * NVERT;
  float mnx=1e30f, mny=1e30f, mnz=1e30f, mxx=-1e30f, mxy=-1e30f, mxz=-1e30f;
  for (int t2 = tid; t2 < NVERT/2; t2 += 1024) {   // 3445 vert-pairs (V even)
    const float* b = vp + t2*6;
    floatx2 A = *(const floatx2*)(b);      // (x0, y0)
    floatx2 B = *(const floatx2*)(b+2);    // (z0, x1)
    floatx2 C = *(const floatx2*)(b+4);    // (y1, z1)
    mnx=fminf(mnx,fminf(A.x,B.y)); mxx=fmaxf(mxx,fmaxf(A.x,B.y));
    mny=fminf(mny,fminf(A.y,C.x)); mxy=fmaxf(mxy,fmaxf(A.y,C.x));
    mnz=fminf(mnz,fminf(B.x,C.y)); mxz=fmaxf(mxz,fmaxf(B.x,C.y));
    floatx2 sx = {A.x+tx, B.y+tx};
    floatx2 sy = {A.y+ty, C.x+ty};
    floatx2 sz = {B.x+tz, C.y+tz};
    *(floatx2*)(o0 + 2*t2) = sx;
    *(floatx2*)(o1 + 2*t2) = sy;
    *(floatx2*)(o2 + 2*t2) = sz;
  }
  mnx=wave_min(mnx)+tx; mny=wave_min(mny)+ty; mnz=wave_min(mnz)+tz;
  mxx=wave_max(mxx)+tx; mxy=wave_max(mxy)+ty; mxz=wave_max(mxz)+tz;
  __shared__ float s[16][6];
  int wave = tid >> 6, lane = tid & 63;
  if (lane == 0) {
    s[wave][0]=mnx; s[wave][1]=mny; s[wave][2]=mnz;
    s[wave][3]=mxx; s[wave][4]=mxy; s[wave][5]=mxz;
  }
  __syncthreads();
  if (tid == 0) {
    float a0=s[0][0],a1=s[0][1],a2=s[0][2],b0=s[0][3],b1=s[0][4],b2=s[0][5];
    for (int w = 1; w < 16; ++w) {
      a0=fminf(a0,s[w][0]); a1=fminf(a1,s[w][1]); a2=fminf(a2,s[w][2]);
      b0=fmaxf(b0,s[w][3]); b1=fmaxf(b1,s[w][4]); b2=fmaxf(b2,s[w][5]);
    }
    bbox[p*3+0]=a0; bbox[p*3+1]=a1; bbox[p*3+2]=a2;              // bmin
    bbox[192+p*3+0]=b0; bbox[192+p*3+1]=b1; bbox[192+p*3+2]=b2;  // bmax
  }
}

// -------- kernel 2: phi pair volume + (block 0) setup outputs [r19] --------
__global__ __launch_bounds__(1024) void k_phi(
    const float* __restrict__ verts, const float* __restrict__ trans,
    const float* __restrict__ bbox, unsigned short* __restrict__ pairs,
    float* __restrict__ centerg,   // [NP][4] = cx,cy,cz,s16
    float* __restrict__ validg, int* __restrict__ jlistg,
    int* __restrict__ jcountg, float* __restrict__ nvg) {
  int p = blockIdx.x >> 2;
  int zq = blockIdx.x & 3;
  int tid = threadIdx.x;
  int x = tid & 31, y = tid >> 5;

  __shared__ float kv[VSUB][3];       // z-culled vertex list
  __shared__ float phib[8][32][32];   // 32 KB
  __shared__ int nkeep;

  const float inv = 1.0f / (float)GRD;
  if (tid == 0) nkeep = 0;
  __syncthreads();

  // center/scale from bbox
  float bx0 = bbox[p*3+0], by0 = bbox[p*3+1], bz0 = bbox[p*3+2];
  float bx1 = bbox[192+p*3+0], by1 = bbox[192+p*3+1], bz1 = bbox[192+p*3+2];
  float cx = 0.5f*(bx0+bx1), cy = 0.5f*(by0+by1), cz = 0.5f*(bz0+bz1);
  float ext = fmaxf(bx1-bx0, fmaxf(by1-by0, bz1-bz0));
  float is = 1.0f / (0.6f * ext);      // (1+0.2)*0.5 * ext

  // zq==0 block publishes person p's center + sample scale
  if (zq == 0 && tid == 0) {
    centerg[p*4+0] = cx; centerg[p*4+1] = cy; centerg[p*4+2] = cz;
    centerg[p*4+3] = is * 16.0f;
  }
  // block 0, wave 0: validity mask / jlist / counts
  if (blockIdx.x == 0 && tid < 64) {
    bool valid = true;
    for (int j = 0; j < NP; ++j) {
      bool ov = true;
      #pragma unroll
      for (int c = 0; c < 3; ++c)
        ov = ov && (bbox[tid*3+c] <= bbox[192+j*3+c]) &&
                   (bbox[j*3+c] <= bbox[192+tid*3+c]);
      valid = valid && ov;
    }
    unsigned long long mm = __ballot(valid);
    if (valid) {
      int pos = (int)__popcll(mm & ((1ull << tid) - 1ull));
      jlistg[pos] = tid;
    }
    validg[tid] = valid ? 1.0f : 0.0f;
    if (tid == 0) {
      jcountg[0] = (int)__popcll(mm);
      nvg[0] = (float)__popcll(mm);
    }
  }

  // z-slab cull: vert can only matter if z-distance to slab range < BAND
  if (tid < VSUB) {
    int v = tid * VSTRIDE;
    const float* vp = verts + (size_t)p * NV3 + (size_t)v * 3;
    float X = (vp[0] + trans[p*3+0] - cx) * is;
    float Y = (vp[1] + trans[p*3+1] - cy) * is;
    float Z = (vp[2] + trans[p*3+2] - cz) * is;
    float zlo = (2.0f*(zq*8)     + 1.0f) * inv - 1.0f;
    float zhi = (2.0f*(zq*8 + 7) + 1.0f) * inv - 1.0f;
    float dz = fmaxf(fmaxf(zlo - Z, Z - zhi), 0.0f);
    if (dz < BAND) {
      int idx = atomicAdd(&nkeep, 1);
      kv[idx][0] = X; kv[idx][1] = Y; kv[idx][2] = Z;
    }
  }
  __syncthreads();
  int nk = nkeep;

  float gx = (2.0f*x + 1.0f) * inv - 1.0f;
  float gy = (2.0f*y + 1.0f) * inv - 1.0f;
  float gz[8];
  #pragma unroll
  for (int k = 0; k < 8; ++k) gz[k] = (2.0f*(zq*8+k) + 1.0f) * inv - 1.0f;

  float d2[8];
  #pragma unroll
  for (int k = 0; k < 8; ++k) d2[k] = 1e30f;

  // per-wave y-row cull: wave w owns rows y = {2w, 2w+1}
  int w = tid >> 6;
  float ylo = (4.0f*w + 1.0f) * inv - 1.0f;
  float yhi = (4.0f*w + 3.0f) * inv - 1.0f;

  for (int v = 0; v < nk; ++v) {
    float Y = kv[v][1];                              // broadcast read
    if (fmaxf(ylo - Y, Y - yhi) >= BAND) continue;   // wave-uniform skip
    float dx = gx - kv[v][0];
    float dy = gy - Y;
    float vzv = kv[v][2];
    float r2 = fmaf(dy, dy, dx*dx);
    #pragma unroll
    for (int k = 0; k < 8; ++k) {
      float dz = gz[k] - vzv;
      d2[k] = fminf(d2[k], fmaf(dz, dz, r2));
    }
  }
  #pragma unroll
  for (int k = 0; k < 8; ++k)
    phib[k][y][x] = fmaxf(BAND - sqrtf(d2[k]), 0.0f) * PHI_SCALE;
  __syncthreads();

  // pair assembly: u16 at (iz, iy, ix); gy = iy-1, gx = ix-1
  unsigned short* qp = pairs + (size_t)p * QVOL;
  for (int idx = tid; idx < QPLANE; idx += 1024) {
    int iy = idx / QDIM, ix = idx % QDIM;
    int gyy = iy - 1, gxx = ix - 1;
    bool gyok = (unsigned)gyy < 32u;
    bool aok = gyok && ((unsigned)gxx < 32u);
    bool bok = gyok && ((unsigned)ix  < 32u);
    int ya = gyok ? gyy : 0;
    int xa = aok ? gxx : 0;
    int xb = bok ? ix : 0;
    #pragma unroll
    for (int k = 0; k < 8; ++k) {
      float a = aok ? phib[k][ya][xa] : 0.0f;
      float b = bok ? phib[k][ya][xb] : 0.0f;
      int pk = __builtin_amdgcn_cvt_pk_fp8_f32(a, b, 0, false);
      qp[(zq*8 + k + 1)*QPLANE + idx] = (unsigned short)(pk & 0xffff);
    }
    if (zq == 0) qp[idx] = 0;                  // plane 0  (gz = -1)
    if (zq == 3) qp[33*QPLANE + idx] = 0;      // plane 33 (gz = 32)
  }
}

// -------- trilinear sample from the LDS pair volume --------
__device__ __forceinline__ float qsample(const unsigned short* q,
                                         float X, float Y, float Z) {
  X = fminf(fmaxf(X, 0.0f), 33.99f);
  Y = fminf(fmaxf(Y, 0.0f), 32.999f);
  Z = fminf(fmaxf(Z, 0.0f), 32.999f);
  float xf = floorf(X), yf = floorf(Y), zf = floorf(Z);
  float fx = X - xf, fy = Y - yf, fz = Z - zf;
  int e = ((int)zf * QDIM + (int)yf) * QDIM + (int)xf;
  unsigned int w00 = q[e];
  unsigned int w10 = q[e + QDIM];
  unsigned int w01 = q[e + QPLANE];
  unsigned int w11 = q[e + QPLANE + QDIM];
  floatx2 c00 = __builtin_amdgcn_cvt_pk_f32_fp8((int)w00, false);
  floatx2 c10 = __builtin_amdgcn_cvt_pk_f32_fp8((int)w10, false);
  floatx2 c01 = __builtin_amdgcn_cvt_pk_f32_fp8((int)w01, false);
  floatx2 c11 = __builtin_amdgcn_cvt_pk_f32_fp8((int)w11, false);
  float u00 = fmaf(fx, c00.y - c00.x, c00.x);
  float u10 = fmaf(fx, c10.y - c10.x, c10.x);
  float u01 = fmaf(fx, c01.y - c01.x, c01.x);
  float u11 = fmaf(fx, c11.y - c11.x, c11.x);
  float a0 = fmaf(fy, u10 - u00, u00);
  float a1 = fmaf(fy, u11 - u01, u01);
  return fmaf(fz, a1 - a0, a0);
}

// -------- kernel 3: 2-slot sample + reduce + last-block finalize --------
// grid = dim3(4, NP): chunk c covers verts c*1792 + {tid, tid+896}.
__global__ __launch_bounds__(896, 7) void k_sample(
    const float* __restrict__ vertsT, const float* __restrict__ centerg,
    const float* __restrict__ validg, const unsigned short* __restrict__ pairs,
    const int* __restrict__ jlistg, const int* __restrict__ jcountg,
    const float* __restrict__ nvg, float* __restrict__ accp,
    unsigned int* __restrict__ donep, float* __restrict__ out) {
  extern __shared__ unsigned char smem[];
  const unsigned short* sq = (const unsigned short*)smem;
  float* red = (float*)(smem + (size_t)QVOL * 2);

  int i = blockIdx.y;
  int tid = threadIdx.x;
  int njl = jcountg[0];

  if (validg[i] != 0.0f) {
    // stage pair volume (78608 B = 4913 uint4) into LDS, immediately
    {
      const uint4* src = (const uint4*)(pairs + (size_t)i * QVOL);
      uint4* dst = (uint4*)smem;
      for (int t = tid; t < QVOL/8; t += 896) dst[t] = src[t];
    }
    __syncthreads();

    int v0 = blockIdx.x * 1792 + tid;       // max 3*1792+895 = 6271 < NVERT
    int v1 = v0 + 896;
    bool ok1 = v1 < NVERT;
    int vc1 = ok1 ? v1 : 0;
    float s16 = centerg[i*4+3];
    // +1 volume-index offset folded: 15.5 + 1 = 16.5
    float bx  = fmaf(-centerg[i*4+0], s16, 16.5f);
    float by  = fmaf(-centerg[i*4+1], s16, 16.5f);
    float bz  = fmaf(-centerg[i*4+2], s16, 16.5f);
    float bx1 = bx + (ok1 ? 0.0f : 1e9f);   // dead slot clamps into zero pad

    float acc = 0.0f;
    #pragma unroll 2
    for (int t = 0; t < njl; ++t) {
      int jj = jlistg[t];                    // uniform -> scalar load/branch
      if (jj == i) continue;
      const float* p0 = vertsT + (size_t)(jj*3) * NVERT;
      float Xa = fmaf(p0[v0],          s16, bx);
      float Ya = fmaf(p0[NVERT+v0],    s16, by);
      float Za = fmaf(p0[2*NVERT+v0],  s16, bz);
      float Xb = fmaf(p0[vc1],         s16, bx1);
      float Yb = fmaf(p0[NVERT+vc1],   s16, by);
      float Zb = fmaf(p0[2*NVERT+vc1], s16, bz);
      acc += qsample(sq, Xa, Ya, Za);
      acc += qsample(sq, Xb, Yb, Zb);
    }

    acc = wave_sum(acc);
    int wv = tid >> 6, lane = tid & 63;
    if (lane == 0) red[wv] = acc;
    __syncthreads();
    if (tid == 0) {
      float tot = 0.0f;
      #pragma unroll
      for (int w = 0; w < 14; ++w) tot += red[w];
      atomicAdd(accp, tot * INV_PHI_SCALE);
    }
  }

  // last-block finalize; every block increments
  if (tid == 0) {
    __threadfence();
    unsigned int old = atomicAdd(donep, 1u);
    if (old == SAMPLE_BLOCKS - 1) {
      float nv = fmaxf(nvg[0], 1.0f);
      float loss = atomicAdd(accp, 0.0f);      // coherent read
      out[0] = loss / (nv * nv);
    }
  }
}

extern "C" void kernel_launch(void* const* d_in, const int* in_sizes, int n_in,
                              void* d_out, int out_size, void* d_ws, size_t ws_size,
                              hipStream_t stream) {
  const float* verts = (const float*)d_in[0];   // [64,6890,3]
  const float* trans = (const float*)d_in[1];   // [64,3]
  float* out = (float*)d_out;

  unsigned short* pairs = (unsigned short*)d_ws;      // 64*39304*2 B = 5.03 MB
  float* vertsT    = (float*)((unsigned char*)d_ws + (size_t)NP * QVOL * 2);
  float* bbox      = vertsT + (size_t)NP * NV3;       // bmin[192] ++ bmax[192]
  float* centerg   = bbox + 384;                      // [NP][4]
  float* validg    = centerg + NP*4;
  float* nvg       = validg + NP;
  float* accp      = nvg + 1;
  unsigned int* donep = (unsigned int*)(accp + 1);
  int* jlistg      = (int*)(donep + 1);
  int* jcountg     = jlistg + NP;

  hipFuncSetAttribute((const void*)k_sample,
                      hipFuncAttributeMaxDynamicSharedMemorySize, LDS_BYTES);

  k_soa_bounds<<<NP, 1024, 0, stream>>>(verts, trans, vertsT, bbox, accp, donep);
  k_phi<<<NP*4, 1024, 0, stream>>>(verts, trans, bbox, pairs, centerg,
                                   validg, jlistg, jcountg, nvg);
  k_sample<<<dim3(4, NP), 896, LDS_BYTES, stream>>>(vertsT, centerg, validg,
                                                    pairs, jlistg, jcountg,
                                                    nvg, accp, donep, out);
}

// Round 22
// 99.711 us; speedup vs baseline: 1.1359x; 1.0351x over previous
//
#include <hip/hip_runtime.h>

// SDFLoss: P=64 people, V=6890 verts, 32^3 SDF-band proxy grid, trilinear
// cross-sampling, scalar loss.
//
// 3 kernels (r19 structure, proven 102.0us; k_phi split to 8 z-slabs):
//   k_soa_bounds : float2-pair vectorized SoA verts + bbox + zero accs [r19]
//   k_phi        : 8 z-slabs/person (512 blocks, 2 blocks/CU, tighter z-cull);
//                  block 0 computes validity/jlist/nv; zq==0 publish center
//   k_sample     : stage pair volume, counted j-loop over global scalar
//                  jlist, last-block finalize               [r19 verbatim]
//
// phi: fully zero-padded PAIR volume, u16 at (iz,iy,ix), idx 0..33 = grid
// -1..32, holding (phi[gx], phi[gx+1]) as 2x fp8(e4m3) scaled x64.
// 34^3 x 2B = 78,608 B -> 2 blocks/CU in k_sample.

#define NP 64
#define NVERT 6890
#define NV3 (NVERT*3)
#define GRD 32
#define QDIM 34                   // -1..32 per axis
#define QPLANE (QDIM*QDIM)        // 1156 entries
#define QVOL (QDIM*QPLANE)        // 39304 entries = 78608 B
#define VSUB 256
#define VSTRIDE 26                // NVERT / VSUB
#define BAND 0.15f
#define PHI_SCALE 64.0f
#define INV_PHI_SCALE 0.015625f
#define LDS_BYTES (QVOL*2 + 64)
#define SAMPLE_BLOCKS (8*NP)

typedef float floatx2 __attribute__((ext_vector_type(2)));

__device__ __forceinline__ float wave_min(float v) {
  #pragma unroll
  for (int off = 32; off > 0; off >>= 1) v = fminf(v, __shfl_down(v, off));
  return v;
}
__device__ __forceinline__ float wave_max(float v) {
  #pragma unroll
  for (int off = 32; off > 0; off >>= 1) v = fmaxf(v, __shfl_down(v, off));
  return v;
}
__device__ __forceinline__ float wave_sum(float v) {
  #pragma unroll
  for (int off = 32; off > 0; off >>= 1) v += __shfl_down(v, off);
  return v;
}

// -------- kernel 1: vectorized SoA verts + bbox + zero accs [r19] --------
__global__ __launch_bounds__(1024) void k_soa_bounds(
    const float* __restrict__ verts, const float* __restrict__ trans,
    float* __restrict__ vertsT, float* __restrict__ bbox,
    float* __restrict__ accp, unsigned int* __restrict__ donep) {
  int p = blockIdx.x;
  int tid = threadIdx.x;
  if (p == 0 && tid == 0) { accp[0] = 0.0f; donep[0] = 0u; }
  const float* vp = verts + (size_t)p * NV3;
  float tx = trans[p*3+0], ty = trans[p*3+1], tz = trans[p*3+2];
  float* o0 = vertsT + (size_t)(p*3+0) * NVERT;
  float* o1 = vertsT + (size_t)(p*3+1) * NVERT;
  float* o2 = vertsT + (size_t)(p*3+2) * NVERT;
  float mnx=1e30f, mny=1e30f, mnz=1e30f, mxx=-1e30f, mxy=-1e30f, mxz=-1e30f;
  for (int t2 = tid; t2 < NVERT/2; t2 += 1024) {   // 3445 vert-pairs (V even)
    const float* b = vp + t2*6;
    floatx2 A = *(const floatx2*)(b);      // (x0, y0)
    floatx2 B = *(const floatx2*)(b+2);    // (z0, x1)
    floatx2 C = *(const floatx2*)(b+4);    // (y1, z1)
    mnx=fminf(mnx,fminf(A.x,B.y)); mxx=fmaxf(mxx,fmaxf(A.x,B.y));
    mny=fminf(mny,fminf(A.y,C.x)); mxy=fmaxf(mxy,fmaxf(A.y,C.x));
    mnz=fminf(mnz,fminf(B.x,C.y)); mxz=fmaxf(mxz,fmaxf(B.x,C.y));
    floatx2 sx = {A.x+tx, B.y+tx};
    floatx2 sy = {A.y+ty, C.x+ty};
    floatx2 sz = {B.x+tz, C.y+tz};
    *(floatx2*)(o0 + 2*t2) = sx;
    *(floatx2*)(o1 + 2*t2) = sy;
    *(floatx2*)(o2 + 2*t2) = sz;
  }
  mnx=wave_min(mnx)+tx; mny=wave_min(mny)+ty; mnz=wave_min(mnz)+tz;
  mxx=wave_max(mxx)+tx; mxy=wave_max(mxy)+ty; mxz=wave_max(mxz)+tz;
  __shared__ float s[16][6];
  int wave = tid >> 6, lane = tid & 63;
  if (lane == 0) {
    s[wave][0]=mnx; s[wave][1]=mny; s[wave][2]=mnz;
    s[wave][3]=mxx; s[wave][4]=mxy; s[wave][5]=mxz;
  }
  __syncthreads();
  if (tid == 0) {
    float a0=s[0][0],a1=s[0][1],a2=s[0][2],b0=s[0][3],b1=s[0][4],b2=s[0][5];
    for (int w = 1; w < 16; ++w) {
      a0=fminf(a0,s[w][0]); a1=fminf(a1,s[w][1]); a2=fminf(a2,s[w][2]);
      b0=fmaxf(b0,s[w][3]); b1=fmaxf(b1,s[w][4]); b2=fmaxf(b2,s[w][5]);
    }
    bbox[p*3+0]=a0; bbox[p*3+1]=a1; bbox[p*3+2]=a2;              // bmin
    bbox[192+p*3+0]=b0; bbox[192+p*3+1]=b1; bbox[192+p*3+2]=b2;  // bmax
  }
}

// -------- kernel 2: phi pair volume, 8 z-slabs + (block 0) setup --------
// grid = NP*8 blocks of 1024 threads: block (p, zq) does z-planes zq*4..zq*4+3.
__global__ __launch_bounds__(1024) void k_phi(
    const float* __restrict__ verts, const float* __restrict__ trans,
    const float* __restrict__ bbox, unsigned short* __restrict__ pairs,
    float* __restrict__ centerg,   // [NP][4] = cx,cy,cz,s16
    float* __restrict__ validg, int* __restrict__ jlistg,
    int* __restrict__ jcountg, float* __restrict__ nvg) {
  int p = blockIdx.x >> 3;
  int zq = blockIdx.x & 7;
  int tid = threadIdx.x;
  int x = tid & 31, y = tid >> 5;

  __shared__ float kv[VSUB][3];       // z-culled vertex list
  __shared__ float phib[4][32][32];   // 16 KB
  __shared__ int nkeep;

  const float inv = 1.0f / (float)GRD;
  if (tid == 0) nkeep = 0;
  __syncthreads();

  // center/scale from bbox
  float bx0 = bbox[p*3+0], by0 = bbox[p*3+1], bz0 = bbox[p*3+2];
  float bx1 = bbox[192+p*3+0], by1 = bbox[192+p*3+1], bz1 = bbox[192+p*3+2];
  float cx = 0.5f*(bx0+bx1), cy = 0.5f*(by0+by1), cz = 0.5f*(bz0+bz1);
  float ext = fmaxf(bx1-bx0, fmaxf(by1-by0, bz1-bz0));
  float is = 1.0f / (0.6f * ext);      // (1+0.2)*0.5 * ext

  // zq==0 block publishes person p's center + sample scale
  if (zq == 0 && tid == 0) {
    centerg[p*4+0] = cx; centerg[p*4+1] = cy; centerg[p*4+2] = cz;
    centerg[p*4+3] = is * 16.0f;
  }
  // block 0, wave 0: validity mask / jlist / counts
  if (blockIdx.x == 0 && tid < 64) {
    bool valid = true;
    for (int j = 0; j < NP; ++j) {
      bool ov = true;
      #pragma unroll
      for (int c = 0; c < 3; ++c)
        ov = ov && (bbox[tid*3+c] <= bbox[192+j*3+c]) &&
                   (bbox[j*3+c] <= bbox[192+tid*3+c]);
      valid = valid && ov;
    }
    unsigned long long mm = __ballot(valid);
    if (valid) {
      int pos = (int)__popcll(mm & ((1ull << tid) - 1ull));
      jlistg[pos] = tid;
    }
    validg[tid] = valid ? 1.0f : 0.0f;
    if (tid == 0) {
      jcountg[0] = (int)__popcll(mm);
      nvg[0] = (float)__popcll(mm);
    }
  }

  // z-slab cull: vert can only matter if z-distance to slab range < BAND
  if (tid < VSUB) {
    int v = tid * VSTRIDE;
    const float* vp = verts + (size_t)p * NV3 + (size_t)v * 3;
    float X = (vp[0] + trans[p*3+0] - cx) * is;
    float Y = (vp[1] + trans[p*3+1] - cy) * is;
    float Z = (vp[2] + trans[p*3+2] - cz) * is;
    float zlo = (2.0f*(zq*4)     + 1.0f) * inv - 1.0f;
    float zhi = (2.0f*(zq*4 + 3) + 1.0f) * inv - 1.0f;
    float dz = fmaxf(fmaxf(zlo - Z, Z - zhi), 0.0f);
    if (dz < BAND) {
      int idx = atomicAdd(&nkeep, 1);
      kv[idx][0] = X; kv[idx][1] = Y; kv[idx][2] = Z;
    }
  }
  __syncthreads();
  int nk = nkeep;

  float gx = (2.0f*x + 1.0f) * inv - 1.0f;
  float gy = (2.0f*y + 1.0f) * inv - 1.0f;
  float gz[4];
  #pragma unroll
  for (int k = 0; k < 4; ++k) gz[k] = (2.0f*(zq*4+k) + 1.0f) * inv - 1.0f;

  float d2[4];
  #pragma unroll
  for (int k = 0; k < 4; ++k) d2[k] = 1e30f;

  // per-wave y-row cull: wave w owns rows y = {2w, 2w+1}
  int w = tid >> 6;
  float ylo = (4.0f*w + 1.0f) * inv - 1.0f;
  float yhi = (4.0f*w + 3.0f) * inv - 1.0f;

  for (int v = 0; v < nk; ++v) {
    float Y = kv[v][1];                              // broadcast read
    if (fmaxf(ylo - Y, Y - yhi) >= BAND) continue;   // wave-uniform skip
    float dx = gx - kv[v][0];
    float dy = gy - Y;
    float vzv = kv[v][2];
    float r2 = fmaf(dy, dy, dx*dx);
    #pragma unroll
    for (int k = 0; k < 4; ++k) {
      float dz = gz[k] - vzv;
      d2[k] = fminf(d2[k], fmaf(dz, dz, r2));
    }
  }
  #pragma unroll
  for (int k = 0; k < 4; ++k)
    phib[k][y][x] = fmaxf(BAND - sqrtf(d2[k]), 0.0f) * PHI_SCALE;
  __syncthreads();

  // pair assembly: u16 at (iz, iy, ix); gy = iy-1, gx = ix-1
  unsigned short* qp = pairs + (size_t)p * QVOL;
  for (int idx = tid; idx < QPLANE; idx += 1024) {
    int iy = idx / QDIM, ix = idx % QDIM;
    int gyy = iy - 1, gxx = ix - 1;
    bool gyok = (unsigned)gyy < 32u;
    bool aok = gyok && ((unsigned)gxx < 32u);
    bool bok = gyok && ((unsigned)ix  < 32u);
    int ya = gyok ? gyy : 0;
    int xa = aok ? gxx : 0;
    int xb = bok ? ix : 0;
    #pragma unroll
    for (int k = 0; k < 4; ++k) {
      float a = aok ? phib[k][ya][xa] : 0.0f;
      float b = bok ? phib[k][ya][xb] : 0.0f;
      int pk = __builtin_amdgcn_cvt_pk_fp8_f32(a, b, 0, false);
      qp[(zq*4 + k + 1)*QPLANE + idx] = (unsigned short)(pk & 0xffff);
    }
    if (zq == 0) qp[idx] = 0;                  // plane 0  (gz = -1)
    if (zq == 7) qp[33*QPLANE + idx] = 0;      // plane 33 (gz = 32)
  }
}

// -------- trilinear sample from the LDS pair volume --------
__device__ __forceinline__ float qsample(const unsigned short* q,
                                         float X, float Y, float Z) {
  X = fminf(fmaxf(X, 0.0f), 33.99f);
  Y = fminf(fmaxf(Y, 0.0f), 32.999f);
  Z = fminf(fmaxf(Z, 0.0f), 32.999f);
  float xf = floorf(X), yf = floorf(Y), zf = floorf(Z);
  float fx = X - xf, fy = Y - yf, fz = Z - zf;
  int e = ((int)zf * QDIM + (int)yf) * QDIM + (int)xf;
  unsigned int w00 = q[e];
  unsigned int w10 = q[e + QDIM];
  unsigned int w01 = q[e + QPLANE];
  unsigned int w11 = q[e + QPLANE + QDIM];
  floatx2 c00 = __builtin_amdgcn_cvt_pk_f32_fp8((int)w00, false);
  floatx2 c10 = __builtin_amdgcn_cvt_pk_f32_fp8((int)w10, false);
  floatx2 c01 = __builtin_amdgcn_cvt_pk_f32_fp8((int)w01, false);
  floatx2 c11 = __builtin_amdgcn_cvt_pk_f32_fp8((int)w11, false);
  float u00 = fmaf(fx, c00.y - c00.x, c00.x);
  float u10 = fmaf(fx, c10.y - c10.x, c10.x);
  float u01 = fmaf(fx, c01.y - c01.x, c01.x);
  float u11 = fmaf(fx, c11.y - c11.x, c11.x);
  float a0 = fmaf(fy, u10 - u00, u00);
  float a1 = fmaf(fy, u11 - u01, u01);
  return fmaf(fz, a1 - a0, a0);
}

// -------- kernel 3: r19-verbatim sample + reduce + last-block finalize ------
__global__ __launch_bounds__(896, 7) void k_sample(
    const float* __restrict__ vertsT, const float* __restrict__ centerg,
    const float* __restrict__ validg, const unsigned short* __restrict__ pairs,
    const int* __restrict__ jlistg, const int* __restrict__ jcountg,
    const float* __restrict__ nvg, float* __restrict__ accp,
    unsigned int* __restrict__ donep, float* __restrict__ out) {
  extern __shared__ unsigned char smem[];
  const unsigned short* sq = (const unsigned short*)smem;
  float* red = (float*)(smem + (size_t)QVOL * 2);

  int i = blockIdx.y;
  int tid = threadIdx.x;
  int njl = jcountg[0];

  if (validg[i] != 0.0f) {
    // stage pair volume (78608 B = 4913 uint4) into LDS, immediately
    {
      const uint4* src = (const uint4*)(pairs + (size_t)i * QVOL);
      uint4* dst = (uint4*)smem;
      for (int t = tid; t < QVOL/8; t += 896) dst[t] = src[t];
    }
    __syncthreads();

    int v = blockIdx.x * 896 + tid;
    bool ok = v < NVERT;
    int vc = ok ? v : 0;
    float s16 = centerg[i*4+3];
    // +1 volume-index offset folded: 15.5 + 1 = 16.5
    float bx = fmaf(-centerg[i*4+0], s16, 16.5f) + (ok ? 0.0f : 1e9f);
    float by = fmaf(-centerg[i*4+1], s16, 16.5f);
    float bz = fmaf(-centerg[i*4+2], s16, 16.5f);

    float acc = 0.0f;
    #pragma unroll 2
    for (int t = 0; t < njl; ++t) {
      int jj = jlistg[t];                      // uniform -> scalar load/branch
      if (jj == i) continue;
      const float* p0 = vertsT + (size_t)(jj*3) * NVERT;
      float X = fmaf(p0[vc],         s16, bx);
      float Y = fmaf(p0[NVERT+vc],   s16, by);
      float Z = fmaf(p0[2*NVERT+vc], s16, bz);
      acc += qsample(sq, X, Y, Z);
    }

    acc = wave_sum(acc);
    int wv = tid >> 6, lane = tid & 63;
    if (lane == 0) red[wv] = acc;
    __syncthreads();
    if (tid == 0) {
      float tot = 0.0f;
      #pragma unroll
      for (int w = 0; w < 14; ++w) tot += red[w];
      atomicAdd(accp, tot * INV_PHI_SCALE);
    }
  }

  // last-block finalize; every block increments
  if (tid == 0) {
    __threadfence();
    unsigned int old = atomicAdd(donep, 1u);
    if (old == SAMPLE_BLOCKS - 1) {
      float nv = fmaxf(nvg[0], 1.0f);
      float loss = atomicAdd(accp, 0.0f);      // coherent read
      out[0] = loss / (nv * nv);
    }
  }
}

extern "C" void kernel_launch(void* const* d_in, const int* in_sizes, int n_in,
                              void* d_out, int out_size, void* d_ws, size_t ws_size,
                              hipStream_t stream) {
  const float* verts = (const float*)d_in[0];   // [64,6890,3]
  const float* trans = (const float*)d_in[1];   // [64,3]
  float* out = (float*)d_out;

  unsigned short* pairs = (unsigned short*)d_ws;      // 64*39304*2 B = 5.03 MB
  float* vertsT    = (float*)((unsigned char*)d_ws + (size_t)NP * QVOL * 2);
  float* bbox      = vertsT + (size_t)NP * NV3;       // bmin[192] ++ bmax[192]
  float* centerg   = bbox + 384;                      // [NP][4]
  float* validg    = centerg + NP*4;
  float* nvg       = validg + NP;
  float* accp      = nvg + 1;
  unsigned int* donep = (unsigned int*)(accp + 1);
  int* jlistg      = (int*)(donep + 1);
  int* jcountg     = jlistg + NP;

  hipFuncSetAttribute((const void*)k_sample,
                      hipFuncAttributeMaxDynamicSharedMemorySize, LDS_BYTES);

  k_soa_bounds<<<NP, 1024, 0, stream>>>(verts, trans, vertsT, bbox, accp, donep);
  k_phi<<<NP*8, 1024, 0, stream>>>(verts, trans, bbox, pairs, centerg,
                                   validg, jlistg, jcountg, nvg);
  k_sample<<<dim3(8, NP), 896, LDS_BYTES, stream>>>(vertsT, centerg, validg,
                                                    pairs, jlistg, jcountg,
                                                    nvg, accp, donep, out);
}